// Round 13
// baseline (651.889 us; speedup 1.0000x reference)
//
#include <hip/hip_runtime.h>
#include <cmath>

#define NN 50000
#define CAP 64               // ELL capacity; P(deg > 64 anywhere) ~ 1e-16 for E=800k

typedef short v8s __attribute__((ext_vector_type(8)));   // 8 x bf16 (4 VGPRs)
typedef float v4f __attribute__((ext_vector_type(4)));

__device__ __forceinline__ float b2f(unsigned short u) {
    return __uint_as_float(((unsigned int)u) << 16);
}
__device__ __forceinline__ unsigned short f2b(float f) {
    unsigned int x = __float_as_uint(f);
    x += 0x7fffu + ((x >> 16) & 1u);          // round-to-nearest-even
    return (unsigned short)(x >> 16);
}

// async global->LDS, 16B per lane. LDS dest must be wave-contiguous (base + lane*16).
__device__ __forceinline__ void gld16(const void* g, void* l) {
    __builtin_amdgcn_global_load_lds(
        (const __attribute__((address_space(1))) unsigned int*)g,
        (__attribute__((address_space(3))) unsigned int*)l, 16, 0, 0);
}

// ---- dtype sniffer: mode=0 -> inputs are bf16, mode=1 -> inputs are float32 ----
__global__ void sniff_kernel(const unsigned short* __restrict__ x, int* __restrict__ mode) {
    __shared__ int c2[2];
    int t = threadIdx.x;                       // 128 threads
    unsigned int e = (x[t] >> 7) & 0xFFu;
    unsigned long long m = __ballot(e >= 100u && e <= 140u);
    if ((t & 63) == 0) c2[t >> 6] = __popcll(m);
    __syncthreads();
    if (t == 0) *mode = (c2[0] + c2[1] >= 112) ? 0 : 1;
}

// ---- ELL fill: one atomic pass, no scan ----
__global__ void fill_kernel(const int* __restrict__ src, const int* __restrict__ dst,
                            int* __restrict__ cnt, unsigned short* __restrict__ ell, int E) {
    int e = blockIdx.x * blockDim.x + threadIdx.x;
    if (e < E) {
        int d = dst[e];
        int pos = atomicAdd(&cnt[d], 1);
        if (pos < CAP) ell[d * CAP + pos] = (unsigned short)src[e];
    }
}

// ---- dinv from counts ----
__global__ void dinv_kernel(const int* __restrict__ cnt, float* __restrict__ dinv, int n) {
    int i = blockIdx.x * blockDim.x + threadIdx.x;
    if (i < n) {
        int d = cnt[i];
        dinv[i] = (d > 0) ? rsqrtf((float)d) : 0.0f;
    }
}

// ---- fused prep: pack x into buf cols 0:128 (ld 512), W->WT bf16, biases ----
__global__ void prep_kernel(const void* __restrict__ x,
                            const void* __restrict__ W1, const void* __restrict__ W2,
                            const void* __restrict__ W3, const void* __restrict__ b1,
                            const void* __restrict__ b2, const void* __restrict__ b3,
                            unsigned short* __restrict__ buf,
                            unsigned short* __restrict__ WT1, unsigned short* __restrict__ WT2,
                            unsigned short* __restrict__ WT3, unsigned short* __restrict__ bb1,
                            unsigned short* __restrict__ bb2, unsigned short* __restrict__ bb3,
                            unsigned short* __restrict__ bbz,
                            const int* __restrict__ modep) {
    int mode = *modep;
    int b = blockIdx.x, t = threadIdx.x;
    if (b < 3125) {                                   // pack x: NN*16 uint4 chunks
        int idx = b * 256 + t;                        // idx < 800000
        int n = idx >> 4, c = idx & 15;
        if (mode == 0) {
            ((uint4*)buf)[n * 64 + c] = ((const uint4*)x)[idx];
        } else {
            const float* xf = (const float*)x + (size_t)idx * 8;
            unsigned short o[8];
#pragma unroll
            for (int i = 0; i < 8; ++i) o[i] = f2b(xf[i]);
            ((uint4*)buf)[n * 64 + c] = *(const uint4*)o;
        }
    } else if (b < 3381) {                            // WT1 [256][256] from W1[256][256]
        int idx = (b - 3125) * 256 + t;
        int n = idx >> 8, k = idx & 255;
        WT1[idx] = mode ? f2b(((const float*)W1)[k * 256 + n])
                        : ((const unsigned short*)W1)[k * 256 + n];
    } else if (b < 3893) {                            // WT2 [256][512] from W2[512][256]
        int idx = (b - 3381) * 256 + t;
        int n = idx >> 9, k = idx & 511;
        WT2[idx] = mode ? f2b(((const float*)W2)[k * 256 + n])
                        : ((const unsigned short*)W2)[k * 256 + n];
    } else if (b < 4149) {                            // WT3 [128][512] from W3[512][128]
        int idx = (b - 3893) * 256 + t;
        int n = idx >> 9, k = idx & 511;
        WT3[idx] = mode ? f2b(((const float*)W3)[k * 128 + n])
                        : ((const unsigned short*)W3)[k * 128 + n];
    } else {                                          // biases
        if (t < 256) {
            bb1[t] = mode ? f2b(((const float*)b1)[t]) : ((const unsigned short*)b1)[t];
            bb2[t] = mode ? f2b(((const float*)b2)[t]) : ((const unsigned short*)b2)[t];
        }
        if (t < 128) {
            bb3[t] = mode ? f2b(((const float*)b3)[t]) : ((const unsigned short*)b3)[t];
            bbz[t] = 0;
        }
    }
}

// ---- SpMM (ELL): EXACT R6 form (scalar tail, 8-deep batches) — any
// restructuring measured as a regression (R2 panels, R5 batch-16, R11 masked
// tail). Structural floor ~55.5us: MSHR x latency capped.
template <int FPL>   // features per lane: F = 64*FPL (2 -> 128, 4 -> 256)
__global__ void spmm_kernel(const unsigned short* __restrict__ h, int ldh,
                            const int* __restrict__ cnt, const unsigned short* __restrict__ ell,
                            const float* __restrict__ dinv,
                            unsigned short* __restrict__ out, int ldo) {
    int node = blockIdx.x * 4 + (threadIdx.x >> 6);
    int lane = threadIdx.x & 63;
    int c = cnt[node]; c = (c < CAP) ? c : CAP;
    int sl = (int)ell[node * CAP + lane];      // coalesced; lanes >= c hold junk (unused)
    float dl = dinv[sl];
    float acc[FPL];
#pragma unroll
    for (int i = 0; i < FPL; ++i) acc[i] = 0.f;
    const int col = lane * FPL;

    int g = 0;
    for (; g + 8 <= c; g += 8) {
        int s[8]; float d[8];
#pragma unroll
        for (int i = 0; i < 8; ++i) { s[i] = __shfl(sl, g + i); d[i] = __shfl(dl, g + i); }
        if (FPL == 4) {
            ushort4 v[8];
#pragma unroll
            for (int i = 0; i < 8; ++i)
                v[i] = *(const ushort4*)(h + (size_t)s[i] * ldh + col);
#pragma unroll
            for (int i = 0; i < 8; ++i) {
                acc[0] += d[i] * b2f(v[i].x); acc[1] += d[i] * b2f(v[i].y);
                acc[2] += d[i] * b2f(v[i].z); acc[3] += d[i] * b2f(v[i].w);
            }
        } else {
            ushort2 v[8];
#pragma unroll
            for (int i = 0; i < 8; ++i)
                v[i] = *(const ushort2*)(h + (size_t)s[i] * ldh + col);
#pragma unroll
            for (int i = 0; i < 8; ++i) {
                acc[0] += d[i] * b2f(v[i].x); acc[1] += d[i] * b2f(v[i].y);
            }
        }
    }
    for (; g < c; ++g) {
        int sg = __shfl(sl, g);
        float dg = __shfl(dl, g);
        const unsigned short* hp = h + (size_t)sg * ldh + col;
        if (FPL == 4) {
            ushort4 v = *(const ushort4*)hp;
            acc[0] += dg * b2f(v.x); acc[1] += dg * b2f(v.y);
            acc[2] += dg * b2f(v.z); acc[3] += dg * b2f(v.w);
        } else {
            ushort2 v = *(const ushort2*)hp;
            acc[0] += dg * b2f(v.x); acc[1] += dg * b2f(v.y);
        }
    }

    float dn = -dinv[node];
    unsigned short* op = out + (size_t)node * ldo + col;
    if (FPL == 4) {
        ushort4 o;
        o.x = f2b(acc[0] * dn); o.y = f2b(acc[1] * dn);
        o.z = f2b(acc[2] * dn); o.w = f2b(acc[3] * dn);
        *(ushort4*)op = o;
    } else {
        ushort2 o;
        o.x = f2b(acc[0] * dn); o.y = f2b(acc[1] * dn);
        *(ushort2*)op = o;
    }
}

// ---- LDS-staged MFMA GEMM — EXACT R6 schedule; all parameters compile-time.
// AV: 0 = none, 1 = bf16 addend, 2 = f32 addend (same rounding class as a
// single longer-K GEMM: partial sum kept in f32 end-to-end).
template <int K32, int NQ, int LDW, int KW0, int AV>
__global__ void __launch_bounds__(2 * NQ * 64)
gemm_lds_kernel(const unsigned short* __restrict__ A, int lda,
                const unsigned short* __restrict__ WT,   // [NQ*64 x LDW] bf16
                const unsigned short* __restrict__ bias, // bf16
                const void* __restrict__ addv, int ldav,  // used iff AV
                void* __restrict__ out, int ldo,
                int M, int dotanh, int is_final, const int* __restrict__ modep) {
    constexpr int NB   = NQ * 64;
    constexpr int NTHR = 2 * NQ * 64;
    constexpr int ACH  = 128 * 4;                     // 16B chunks of A tile
    constexpr int BCH  = NB * 4;
    constexpr int ROUNDS = (ACH + BCH) / NTHR;
    constexpr int LDSZ  = (128 + NB) * 32;            // ushorts per buffer
    __shared__ unsigned short lds[2 * LDSZ];          // double-buffered A|B tiles

    const int tid = threadIdx.x;
    const int wave = tid >> 6, lane = tid & 63, quad = lane >> 4, l16 = lane & 15;
    const int mh = wave / NQ, nq = wave % NQ;
    const int m0 = blockIdx.x * 128;

    v4f acc[4][4];
#pragma unroll
    for (int mi = 0; mi < 4; ++mi)
#pragma unroll
        for (int ni = 0; ni < 4; ++ni) acc[mi][ni] = (v4f){0.f, 0.f, 0.f, 0.f};

    const unsigned short* gp[ROUNDS];
#pragma unroll
    for (int r = 0; r < ROUNDS; ++r) {
        int c = tid + r * NTHR;
        if (c < ACH) {
            int row = m0 + (c >> 2);
            if (row >= M) row = M - 1;
            gp[r] = A + (size_t)row * lda + (c & 3) * 8;
        } else {
            int cb = c - ACH;
            gp[r] = WT + (size_t)(cb >> 2) * LDW + KW0 + (cb & 3) * 8;
        }
    }

    auto STAGE = [&](int bsel, int k0) {
#pragma unroll
        for (int r = 0; r < ROUNDS; ++r) {
            int c = tid + r * NTHR;
            gld16(gp[r] + k0, (void*)&lds[bsel * LDSZ + c * 8]);
        }
    };

    STAGE(0, 0);                                      // prologue: tile 0 in flight
#pragma unroll 1
    for (int t = 0; t < K32; ++t) {
        if (t + 1 < K32) {
            STAGE((t + 1) & 1, (t + 1) * 32);         // issue next FIRST
            asm volatile("s_waitcnt vmcnt(%0)" :: "i"(ROUNDS) : "memory");  // t's landed
        } else {
            asm volatile("s_waitcnt vmcnt(0)" ::: "memory");
        }
        __builtin_amdgcn_s_barrier();                 // t's tile visible to all waves

        const unsigned short* aT = &lds[(t & 1) * LDSZ];
        const unsigned short* bT = aT + 128 * 32;
        v8s a_frag[4], b_frag[4];
#pragma unroll
        for (int mi = 0; mi < 4; ++mi)
            a_frag[mi] = *(const v8s*)&aT[(mh * 64 + mi * 16 + l16) * 32 + quad * 8];
#pragma unroll
        for (int ni = 0; ni < 4; ++ni)
            b_frag[ni] = *(const v8s*)&bT[(nq * 64 + ni * 16 + l16) * 32 + quad * 8];
#pragma unroll
        for (int mi = 0; mi < 4; ++mi)
#pragma unroll
            for (int ni = 0; ni < 4; ++ni)
                acc[mi][ni] = __builtin_amdgcn_mfma_f32_16x16x32_bf16(a_frag[mi], b_frag[ni],
                                                                      acc[mi][ni], 0, 0, 0);
        asm volatile("s_waitcnt lgkmcnt(0)" ::: "memory");   // my ds_reads retired
        __builtin_amdgcn_s_barrier();                 // safe to overwrite buf[t&1]
    }

    int fin = is_final ? *modep : 0;
#pragma unroll
    for (int ni = 0; ni < 4; ++ni) {
        int colc = nq * 64 + ni * 16 + l16;
        float bv = b2f(bias[colc]);
#pragma unroll
        for (int mi = 0; mi < 4; ++mi) {
#pragma unroll
            for (int r = 0; r < 4; ++r) {
                int row = m0 + mh * 64 + mi * 16 + quad * 4 + r;
                if (row < M) {
                    float v = acc[mi][ni][r] + bv;
                    if constexpr (AV == 1)
                        v += b2f(((const unsigned short*)addv)[(size_t)row * ldav + colc]);
                    if constexpr (AV == 2)
                        v += ((const float*)addv)[(size_t)row * ldav + colc];
                    if (dotanh) v = tanhf(v);
                    if (fin) ((float*)out)[(size_t)row * ldo + colc] = v;
                    else     ((unsigned short*)out)[(size_t)row * ldo + colc] = f2b(v);
                }
            }
        }
    }
}

// ---- FUSED mid-layer kernel: blocks [0,GB) compute ztop = h @ W_top (K=256,
// f32 out, no bias/tanh); blocks [GB, GB+SB) run the proven spmm body (8 nodes
// x 8 waves). Independent work (both read h; write disjoint buffers) co-resides
// on each CU: 1 spmm block (8 waves x 8-deep = ~64 outstanding lines, the MSHR
// cap per R5) saturates the gather machinery while GEMM blocks use MFMA+LDS.
template <int K32, int NQ, int LDW, int KW0>
__global__ void __launch_bounds__(512)
fused_kernel(const unsigned short* __restrict__ h, int lda,
             const unsigned short* __restrict__ WT,
             float* __restrict__ ztop, int ldz, int GB, int M,
             const int* __restrict__ cnt, const unsigned short* __restrict__ ell,
             const float* __restrict__ dinv,
             unsigned short* __restrict__ x1out, int ldo1) {
    constexpr int NB   = NQ * 64;
    constexpr int NTHR = 2 * NQ * 64;                 // 512
    constexpr int ACH  = 128 * 4;
    constexpr int BCH  = NB * 4;
    constexpr int ROUNDS = (ACH + BCH) / NTHR;
    constexpr int LDSZ  = (128 + NB) * 32;
    __shared__ unsigned short lds[2 * LDSZ];

    if ((int)blockIdx.x < GB) {
        // ---------------- GEMM-top role (R6-proven schedule) ----------------
        const int tid = threadIdx.x;
        const int wave = tid >> 6, lane = tid & 63, quad = lane >> 4, l16 = lane & 15;
        const int mh = wave / NQ, nq = wave % NQ;
        const int m0 = blockIdx.x * 128;

        v4f acc[4][4];
#pragma unroll
        for (int mi = 0; mi < 4; ++mi)
#pragma unroll
            for (int ni = 0; ni < 4; ++ni) acc[mi][ni] = (v4f){0.f, 0.f, 0.f, 0.f};

        const unsigned short* gp[ROUNDS];
#pragma unroll
        for (int r = 0; r < ROUNDS; ++r) {
            int c = tid + r * NTHR;
            if (c < ACH) {
                int row = m0 + (c >> 2);
                if (row >= M) row = M - 1;
                gp[r] = h + (size_t)row * lda + (c & 3) * 8;
            } else {
                int cb = c - ACH;
                gp[r] = WT + (size_t)(cb >> 2) * LDW + KW0 + (cb & 3) * 8;
            }
        }

        auto STAGE = [&](int bsel, int k0) {
#pragma unroll
            for (int r = 0; r < ROUNDS; ++r) {
                int c = tid + r * NTHR;
                gld16(gp[r] + k0, (void*)&lds[bsel * LDSZ + c * 8]);
            }
        };

        STAGE(0, 0);
#pragma unroll 1
        for (int t = 0; t < K32; ++t) {
            if (t + 1 < K32) {
                STAGE((t + 1) & 1, (t + 1) * 32);
                asm volatile("s_waitcnt vmcnt(%0)" :: "i"(ROUNDS) : "memory");
            } else {
                asm volatile("s_waitcnt vmcnt(0)" ::: "memory");
            }
            __builtin_amdgcn_s_barrier();

            const unsigned short* aT = &lds[(t & 1) * LDSZ];
            const unsigned short* bT = aT + 128 * 32;
            v8s a_frag[4], b_frag[4];
#pragma unroll
            for (int mi = 0; mi < 4; ++mi)
                a_frag[mi] = *(const v8s*)&aT[(mh * 64 + mi * 16 + l16) * 32 + quad * 8];
#pragma unroll
            for (int ni = 0; ni < 4; ++ni)
                b_frag[ni] = *(const v8s*)&bT[(nq * 64 + ni * 16 + l16) * 32 + quad * 8];
#pragma unroll
            for (int mi = 0; mi < 4; ++mi)
#pragma unroll
                for (int ni = 0; ni < 4; ++ni)
                    acc[mi][ni] = __builtin_amdgcn_mfma_f32_16x16x32_bf16(
                        a_frag[mi], b_frag[ni], acc[mi][ni], 0, 0, 0);
            asm volatile("s_waitcnt lgkmcnt(0)" ::: "memory");
            __builtin_amdgcn_s_barrier();
        }

#pragma unroll
        for (int ni = 0; ni < 4; ++ni) {
            int colc = nq * 64 + ni * 16 + l16;
#pragma unroll
            for (int mi = 0; mi < 4; ++mi) {
#pragma unroll
                for (int r = 0; r < 4; ++r) {
                    int row = m0 + mh * 64 + mi * 16 + quad * 4 + r;
                    if (row < M) ztop[(size_t)row * ldz + colc] = acc[mi][ni][r];
                }
            }
        }
    } else {
        // ---------------- spmm role (R6-proven body, FPL=4) ----------------
        int node = ((int)blockIdx.x - GB) * 8 + (threadIdx.x >> 6);
        int lane = threadIdx.x & 63;
        if (node >= NN) return;
        int c = cnt[node]; c = (c < CAP) ? c : CAP;
        int sl = (int)ell[node * CAP + lane];
        float dl = dinv[sl];
        float a0 = 0.f, a1 = 0.f, a2 = 0.f, a3 = 0.f;
        const int col = lane * 4;

        int g = 0;
        for (; g + 8 <= c; g += 8) {
            int s[8]; float d[8];
#pragma unroll
            for (int i = 0; i < 8; ++i) { s[i] = __shfl(sl, g + i); d[i] = __shfl(dl, g + i); }
            ushort4 v[8];
#pragma unroll
            for (int i = 0; i < 8; ++i)
                v[i] = *(const ushort4*)(h + (size_t)s[i] * lda + col);
#pragma unroll
            for (int i = 0; i < 8; ++i) {
                a0 += d[i] * b2f(v[i].x); a1 += d[i] * b2f(v[i].y);
                a2 += d[i] * b2f(v[i].z); a3 += d[i] * b2f(v[i].w);
            }
        }
        for (; g < c; ++g) {
            int sg = __shfl(sl, g);
            float dg = __shfl(dl, g);
            ushort4 v = *(const ushort4*)(h + (size_t)sg * lda + col);
            a0 += dg * b2f(v.x); a1 += dg * b2f(v.y);
            a2 += dg * b2f(v.z); a3 += dg * b2f(v.w);
        }
        float dn = -dinv[node];
        ushort4 o;
        o.x = f2b(a0 * dn); o.y = f2b(a1 * dn);
        o.z = f2b(a2 * dn); o.w = f2b(a3 * dn);
        *(ushort4*)(x1out + (size_t)node * ldo1 + col) = o;
    }
}

static inline size_t al256(size_t x) { return (x + 255) & ~(size_t)255; }

extern "C" void kernel_launch(void* const* d_in, const int* in_sizes, int n_in,
                              void* d_out, int out_size, void* d_ws, size_t ws_size,
                              hipStream_t stream) {
    const void* x  = d_in[0];
    const int* src = (const int*)d_in[1];
    const int* dst = (const int*)d_in[2];
    const void* W1 = d_in[3]; const void* b1 = d_in[4];
    const void* W2 = d_in[5]; const void* b2 = d_in[6];
    const void* W3 = d_in[7]; const void* b3 = d_in[8];
    const int E = in_sizes[1];

    // workspace carve-up (R12 layout + ztop appended; ~110 MB with ztop)
    char* p = (char*)d_ws;
    int* mode     = (int*)p;            p += 256;
    int* cnt      = (int*)p;            p += al256((size_t)NN * 4);
    float* dinv   = (float*)p;          p += al256((size_t)NN * 4);
    unsigned short* ell = (unsigned short*)p; p += al256((size_t)NN * CAP * 2);
    unsigned short* WT1 = (unsigned short*)p; p += al256((size_t)256 * 256 * 2);
    unsigned short* WT2 = (unsigned short*)p; p += al256((size_t)256 * 512 * 2);
    unsigned short* WT3 = (unsigned short*)p; p += al256((size_t)128 * 512 * 2);
    unsigned short* bb1 = (unsigned short*)p; p += al256((size_t)256 * 2);
    unsigned short* bb2 = (unsigned short*)p; p += al256((size_t)256 * 2);
    unsigned short* bb3 = (unsigned short*)p; p += al256((size_t)128 * 2);
    unsigned short* bbz = (unsigned short*)p; p += al256((size_t)128 * 2);
    unsigned short* buf = (unsigned short*)p; p += al256((size_t)NN * 512 * 2);
    float* ztop   = (float*)p;          p += al256((size_t)NN * 256 * 4);
    bool can_fuse = ((size_t)(p - (char*)d_ws) <= ws_size);

    hipMemsetAsync(cnt, 0, (size_t)NN * 4, stream);
    sniff_kernel<<<1, 128, 0, stream>>>((const unsigned short*)x, mode);
    prep_kernel<<<4150, 256, 0, stream>>>(x, W1, W2, W3, b1, b2, b3,
                                          buf, WT1, WT2, WT3, bb1, bb2, bb3, bbz, mode);
    int eb = (E + 255) / 256;
    fill_kernel<<<eb, 256, 0, stream>>>(src, dst, cnt, ell, E);
    dinv_kernel<<<(NN + 255) / 256, 256, 0, stream>>>(cnt, dinv, NN);

    const int SPMM_GRID = NN / 4;          // 4 waves (nodes) per 256-thread block
    const int GB = (NN + 127) / 128;       // 391 gemm row-blocks
    const int SB = (NN + 7) / 8;           // 6250 fused spmm role-blocks

    // L1: buf = [x(0:128) | x1(128:256)]; gemm K=256 in-place -> cols 0:256
    spmm_kernel<2><<<SPMM_GRID, 256, 0, stream>>>(buf, 512, cnt, ell, dinv, buf + 128, 512);
    gemm_lds_kernel<8, 4, 256, 0, 0><<<GB, 512, 0, stream>>>(
        buf, 512, WT1, bb1, nullptr, 0, buf, 512, NN, 1, 0, mode);

    // L2..L4
    for (int l = 0; l < 3; ++l) {
        if (can_fuse) {
            // fused: ztop = h @ W2_top (K=256)  ||  x1 = Â h   (co-resident)
            fused_kernel<8, 4, 512, 0><<<GB + SB, 512, 0, stream>>>(
                buf, 512, WT2, ztop, 256, GB, NN, cnt, ell, dinv, buf + 256, 512);
            // h' = tanh(x1 @ W2_bot + ztop + b2)  (f32 addend: same rounding class)
            gemm_lds_kernel<8, 4, 512, 256, 2><<<GB, 512, 0, stream>>>(
                buf + 256, 512, WT2, bb2, ztop, 256, buf, 512, NN, 1, 0, mode);
        } else {
            spmm_kernel<4><<<SPMM_GRID, 256, 0, stream>>>(buf, 512, cnt, ell, dinv,
                                                          buf + 256, 512);
            gemm_lds_kernel<16, 4, 512, 0, 0><<<GB, 512, 0, stream>>>(
                buf, 512, WT2, bb2, nullptr, 0, buf, 512, NN, 1, 0, mode);
        }
    }

    // L5 swap (R12-proven): z = h @ W3bot; x1z = Âz (FPL=2); out = h @ W3top + x1z + b3
    gemm_lds_kernel<8, 2, 512, 256, 0><<<GB, 256, 0, stream>>>(
        buf, 512, WT3, bbz, nullptr, 0, buf + 256, 512, NN, 0, 0, mode);
    spmm_kernel<2><<<SPMM_GRID, 256, 0, stream>>>(buf + 256, 512, cnt, ell, dinv,
                                                  buf + 384, 512);
    gemm_lds_kernel<8, 2, 512, 0, 1><<<GB, 256, 0, stream>>>(
        buf, 512, WT3, bb3, buf + 384, 512, d_out, 128, NN, 0, 1, mode);
}

// Round 14
// 540.109 us; speedup vs baseline: 1.2070x; 1.2070x over previous
//
#include <hip/hip_runtime.h>
#include <cmath>

#define NN 50000
#define CAP 64               // ELL capacity; P(deg > 64 anywhere) ~ 1e-16 for E=800k

typedef short v8s __attribute__((ext_vector_type(8)));   // 8 x bf16 (4 VGPRs)
typedef float v4f __attribute__((ext_vector_type(4)));

__device__ __forceinline__ float b2f(unsigned short u) {
    return __uint_as_float(((unsigned int)u) << 16);
}
__device__ __forceinline__ unsigned short f2b(float f) {
    unsigned int x = __float_as_uint(f);
    x += 0x7fffu + ((x >> 16) & 1u);          // round-to-nearest-even
    return (unsigned short)(x >> 16);
}

// async global->LDS, 16B per lane. LDS dest must be wave-contiguous (base + lane*16).
__device__ __forceinline__ void gld16(const void* g, void* l) {
    __builtin_amdgcn_global_load_lds(
        (const __attribute__((address_space(1))) unsigned int*)g,
        (__attribute__((address_space(3))) unsigned int*)l, 16, 0, 0);
}

// ---- dtype sniffer: mode=0 -> inputs are bf16, mode=1 -> inputs are float32 ----
__global__ void sniff_kernel(const unsigned short* __restrict__ x, int* __restrict__ mode) {
    __shared__ int c2[2];
    int t = threadIdx.x;                       // 128 threads
    unsigned int e = (x[t] >> 7) & 0xFFu;
    unsigned long long m = __ballot(e >= 100u && e <= 140u);
    if ((t & 63) == 0) c2[t >> 6] = __popcll(m);
    __syncthreads();
    if (t == 0) *mode = (c2[0] + c2[1] >= 112) ? 0 : 1;
}

// ---- ELL fill: one atomic pass, no scan ----
__global__ void fill_kernel(const int* __restrict__ src, const int* __restrict__ dst,
                            int* __restrict__ cnt, unsigned short* __restrict__ ell, int E) {
    int e = blockIdx.x * blockDim.x + threadIdx.x;
    if (e < E) {
        int d = dst[e];
        int pos = atomicAdd(&cnt[d], 1);
        if (pos < CAP) ell[d * CAP + pos] = (unsigned short)src[e];
    }
}

// ---- dinv from counts ----
__global__ void dinv_kernel(const int* __restrict__ cnt, float* __restrict__ dinv, int n) {
    int i = blockIdx.x * blockDim.x + threadIdx.x;
    if (i < n) {
        int d = cnt[i];
        dinv[i] = (d > 0) ? rsqrtf((float)d) : 0.0f;
    }
}

// ---- fused prep: pack x into buf cols 0:128 (ld 512), W->WT bf16, biases ----
__global__ void prep_kernel(const void* __restrict__ x,
                            const void* __restrict__ W1, const void* __restrict__ W2,
                            const void* __restrict__ W3, const void* __restrict__ b1,
                            const void* __restrict__ b2, const void* __restrict__ b3,
                            unsigned short* __restrict__ buf,
                            unsigned short* __restrict__ WT1, unsigned short* __restrict__ WT2,
                            unsigned short* __restrict__ WT3, unsigned short* __restrict__ bb1,
                            unsigned short* __restrict__ bb2, unsigned short* __restrict__ bb3,
                            unsigned short* __restrict__ bbz,
                            const int* __restrict__ modep) {
    int mode = *modep;
    int b = blockIdx.x, t = threadIdx.x;
    if (b < 3125) {                                   // pack x: NN*16 uint4 chunks
        int idx = b * 256 + t;                        // idx < 800000
        int n = idx >> 4, c = idx & 15;
        if (mode == 0) {
            ((uint4*)buf)[n * 64 + c] = ((const uint4*)x)[idx];
        } else {
            const float* xf = (const float*)x + (size_t)idx * 8;
            unsigned short o[8];
#pragma unroll
            for (int i = 0; i < 8; ++i) o[i] = f2b(xf[i]);
            ((uint4*)buf)[n * 64 + c] = *(const uint4*)o;
        }
    } else if (b < 3381) {                            // WT1 [256][256] from W1[256][256]
        int idx = (b - 3125) * 256 + t;
        int n = idx >> 8, k = idx & 255;
        WT1[idx] = mode ? f2b(((const float*)W1)[k * 256 + n])
                        : ((const unsigned short*)W1)[k * 256 + n];
    } else if (b < 3893) {                            // WT2 [256][512] from W2[512][256]
        int idx = (b - 3381) * 256 + t;
        int n = idx >> 9, k = idx & 511;
        WT2[idx] = mode ? f2b(((const float*)W2)[k * 256 + n])
                        : ((const unsigned short*)W2)[k * 256 + n];
    } else if (b < 4149) {                            // WT3 [128][512] from W3[512][128]
        int idx = (b - 3893) * 256 + t;
        int n = idx >> 9, k = idx & 511;
        WT3[idx] = mode ? f2b(((const float*)W3)[k * 128 + n])
                        : ((const unsigned short*)W3)[k * 128 + n];
    } else {                                          // biases
        if (t < 256) {
            bb1[t] = mode ? f2b(((const float*)b1)[t]) : ((const unsigned short*)b1)[t];
            bb2[t] = mode ? f2b(((const float*)b2)[t]) : ((const unsigned short*)b2)[t];
        }
        if (t < 128) {
            bb3[t] = mode ? f2b(((const float*)b3)[t]) : ((const unsigned short*)b3)[t];
            bbz[t] = 0;
        }
    }
}

// ---- SpMM (ELL): EXACT R6 form (scalar tail, 8-deep batches) — any
// restructuring measured as a regression (R2 panels, R5 batch-16, R11 masked
// tail, R13 co-schedule). Structural floor ~55.5us: MSHR x latency capped.
template <int FPL>   // features per lane: F = 64*FPL (2 -> 128, 4 -> 256)
__global__ void spmm_kernel(const unsigned short* __restrict__ h, int ldh,
                            const int* __restrict__ cnt, const unsigned short* __restrict__ ell,
                            const float* __restrict__ dinv,
                            unsigned short* __restrict__ out, int ldo) {
    int node = blockIdx.x * 4 + (threadIdx.x >> 6);
    int lane = threadIdx.x & 63;
    int c = cnt[node]; c = (c < CAP) ? c : CAP;
    int sl = (int)ell[node * CAP + lane];      // coalesced; lanes >= c hold junk (unused)
    float dl = dinv[sl];
    float acc[FPL];
#pragma unroll
    for (int i = 0; i < FPL; ++i) acc[i] = 0.f;
    const int col = lane * FPL;

    int g = 0;
    for (; g + 8 <= c; g += 8) {
        int s[8]; float d[8];
#pragma unroll
        for (int i = 0; i < 8; ++i) { s[i] = __shfl(sl, g + i); d[i] = __shfl(dl, g + i); }
        if (FPL == 4) {
            ushort4 v[8];
#pragma unroll
            for (int i = 0; i < 8; ++i)
                v[i] = *(const ushort4*)(h + (size_t)s[i] * ldh + col);
#pragma unroll
            for (int i = 0; i < 8; ++i) {
                acc[0] += d[i] * b2f(v[i].x); acc[1] += d[i] * b2f(v[i].y);
                acc[2] += d[i] * b2f(v[i].z); acc[3] += d[i] * b2f(v[i].w);
            }
        } else {
            ushort2 v[8];
#pragma unroll
            for (int i = 0; i < 8; ++i)
                v[i] = *(const ushort2*)(h + (size_t)s[i] * ldh + col);
#pragma unroll
            for (int i = 0; i < 8; ++i) {
                acc[0] += d[i] * b2f(v[i].x); acc[1] += d[i] * b2f(v[i].y);
            }
        }
    }
    for (; g < c; ++g) {
        int sg = __shfl(sl, g);
        float dg = __shfl(dl, g);
        const unsigned short* hp = h + (size_t)sg * ldh + col;
        if (FPL == 4) {
            ushort4 v = *(const ushort4*)hp;
            acc[0] += dg * b2f(v.x); acc[1] += dg * b2f(v.y);
            acc[2] += dg * b2f(v.z); acc[3] += dg * b2f(v.w);
        } else {
            ushort2 v = *(const ushort2*)hp;
            acc[0] += dg * b2f(v.x); acc[1] += dg * b2f(v.y);
        }
    }

    float dn = -dinv[node];
    unsigned short* op = out + (size_t)node * ldo + col;
    if (FPL == 4) {
        ushort4 o;
        o.x = f2b(acc[0] * dn); o.y = f2b(acc[1] * dn);
        o.z = f2b(acc[2] * dn); o.w = f2b(acc[3] * dn);
        *(ushort4*)op = o;
    } else {
        ushort2 o;
        o.x = f2b(acc[0] * dn); o.y = f2b(acc[1] * dn);
        *(ushort2*)op = o;
    }
}

// ---- LDS-staged MFMA GEMM — EXACT R6 schedule; ALL new parameters are
// compile-time (LDW = B row stride, KW0 = B column offset, ADDV = epilogue
// addend) so the main-layer instantiations codegen identically to R6.
// R11 measured the runtime-parameterized version at 71us vs R6's ~55: the
// runtime addv/ldw path was the regression. Block covers full output width ->
// owns its rows -> in-place safe.
template <int K32, int NQ, int LDW, int KW0, bool ADDV>
__global__ void __launch_bounds__(2 * NQ * 64)
gemm_lds_kernel(const unsigned short* __restrict__ A, int lda,
                const unsigned short* __restrict__ WT,   // [NQ*64 x LDW] bf16
                const unsigned short* __restrict__ bias, // bf16
                const unsigned short* __restrict__ addv, int ldav,  // used iff ADDV
                void* __restrict__ out, int ldo,
                int M, int dotanh, int is_final, const int* __restrict__ modep) {
    constexpr int NB   = NQ * 64;
    constexpr int NTHR = 2 * NQ * 64;
    constexpr int ACH  = 128 * 4;                     // 16B chunks of A tile
    constexpr int BCH  = NB * 4;
    constexpr int ROUNDS = (ACH + BCH) / NTHR;
    constexpr int LDSZ  = (128 + NB) * 32;            // ushorts per buffer
    __shared__ unsigned short lds[2 * LDSZ];          // double-buffered A|B tiles

    const int tid = threadIdx.x;
    const int wave = tid >> 6, lane = tid & 63, quad = lane >> 4, l16 = lane & 15;
    const int mh = wave / NQ, nq = wave % NQ;
    const int m0 = blockIdx.x * 128;

    v4f acc[4][4];
#pragma unroll
    for (int mi = 0; mi < 4; ++mi)
#pragma unroll
        for (int ni = 0; ni < 4; ++ni) acc[mi][ni] = (v4f){0.f, 0.f, 0.f, 0.f};

    const unsigned short* gp[ROUNDS];
#pragma unroll
    for (int r = 0; r < ROUNDS; ++r) {
        int c = tid + r * NTHR;
        if (c < ACH) {
            int row = m0 + (c >> 2);
            if (row >= M) row = M - 1;
            gp[r] = A + (size_t)row * lda + (c & 3) * 8;
        } else {
            int cb = c - ACH;
            gp[r] = WT + (size_t)(cb >> 2) * LDW + KW0 + (cb & 3) * 8;
        }
    }

    auto STAGE = [&](int bsel, int k0) {
#pragma unroll
        for (int r = 0; r < ROUNDS; ++r) {
            int c = tid + r * NTHR;
            gld16(gp[r] + k0, (void*)&lds[bsel * LDSZ + c * 8]);
        }
    };

    STAGE(0, 0);                                      // prologue: tile 0 in flight
#pragma unroll 1
    for (int t = 0; t < K32; ++t) {
        if (t + 1 < K32) {
            STAGE((t + 1) & 1, (t + 1) * 32);         // issue next FIRST
            asm volatile("s_waitcnt vmcnt(%0)" :: "i"(ROUNDS) : "memory");  // t's landed
        } else {
            asm volatile("s_waitcnt vmcnt(0)" ::: "memory");
        }
        __builtin_amdgcn_s_barrier();                 // t's tile visible to all waves

        const unsigned short* aT = &lds[(t & 1) * LDSZ];
        const unsigned short* bT = aT + 128 * 32;
        v8s a_frag[4], b_frag[4];
#pragma unroll
        for (int mi = 0; mi < 4; ++mi)
            a_frag[mi] = *(const v8s*)&aT[(mh * 64 + mi * 16 + l16) * 32 + quad * 8];
#pragma unroll
        for (int ni = 0; ni < 4; ++ni)
            b_frag[ni] = *(const v8s*)&bT[(nq * 64 + ni * 16 + l16) * 32 + quad * 8];
#pragma unroll
        for (int mi = 0; mi < 4; ++mi)
#pragma unroll
            for (int ni = 0; ni < 4; ++ni)
                acc[mi][ni] = __builtin_amdgcn_mfma_f32_16x16x32_bf16(a_frag[mi], b_frag[ni],
                                                                      acc[mi][ni], 0, 0, 0);
        asm volatile("s_waitcnt lgkmcnt(0)" ::: "memory");   // my ds_reads retired
        __builtin_amdgcn_s_barrier();                 // safe to overwrite buf[t&1]
    }

    int fin = is_final ? *modep : 0;
#pragma unroll
    for (int ni = 0; ni < 4; ++ni) {
        int colc = nq * 64 + ni * 16 + l16;
        float bv = b2f(bias[colc]);
#pragma unroll
        for (int mi = 0; mi < 4; ++mi) {
#pragma unroll
            for (int r = 0; r < 4; ++r) {
                int row = m0 + mh * 64 + mi * 16 + quad * 4 + r;
                if (row < M) {
                    float v = acc[mi][ni][r] + bv;
                    if constexpr (ADDV) v += b2f(addv[(size_t)row * ldav + colc]);
                    if (dotanh) v = tanhf(v);
                    if (fin) ((float*)out)[(size_t)row * ldo + colc] = v;
                    else     ((unsigned short*)out)[(size_t)row * ldo + colc] = f2b(v);
                }
            }
        }
    }
}

static inline size_t al256(size_t x) { return (x + 255) & ~(size_t)255; }

extern "C" void kernel_launch(void* const* d_in, const int* in_sizes, int n_in,
                              void* d_out, int out_size, void* d_ws, size_t ws_size,
                              hipStream_t stream) {
    const void* x  = d_in[0];
    const int* src = (const int*)d_in[1];
    const int* dst = (const int*)d_in[2];
    const void* W1 = d_in[3]; const void* b1 = d_in[4];
    const void* W2 = d_in[5]; const void* b2 = d_in[6];
    const void* W3 = d_in[7]; const void* b3 = d_in[8];
    const int E = in_sizes[1];

    // workspace carve-up (~58.6 MB)
    char* p = (char*)d_ws;
    int* mode     = (int*)p;            p += 256;
    int* cnt      = (int*)p;            p += al256((size_t)NN * 4);
    float* dinv   = (float*)p;          p += al256((size_t)NN * 4);
    unsigned short* ell = (unsigned short*)p; p += al256((size_t)NN * CAP * 2);
    unsigned short* WT1 = (unsigned short*)p; p += al256((size_t)256 * 256 * 2);
    unsigned short* WT2 = (unsigned short*)p; p += al256((size_t)256 * 512 * 2);
    unsigned short* WT3 = (unsigned short*)p; p += al256((size_t)128 * 512 * 2);
    unsigned short* bb1 = (unsigned short*)p; p += al256((size_t)256 * 2);
    unsigned short* bb2 = (unsigned short*)p; p += al256((size_t)256 * 2);
    unsigned short* bb3 = (unsigned short*)p; p += al256((size_t)128 * 2);
    unsigned short* bbz = (unsigned short*)p; p += al256((size_t)128 * 2);
    unsigned short* buf = (unsigned short*)p; p += al256((size_t)NN * 512 * 2);

    hipMemsetAsync(cnt, 0, (size_t)NN * 4, stream);
    sniff_kernel<<<1, 128, 0, stream>>>((const unsigned short*)x, mode);
    prep_kernel<<<4150, 256, 0, stream>>>(x, W1, W2, W3, b1, b2, b3,
                                          buf, WT1, WT2, WT3, bb1, bb2, bb3, bbz, mode);
    int eb = (E + 255) / 256;
    fill_kernel<<<eb, 256, 0, stream>>>(src, dst, cnt, ell, E);
    dinv_kernel<<<(NN + 255) / 256, 256, 0, stream>>>(cnt, dinv, NN);

    const int SPMM_GRID = NN / 4;          // 4 waves (nodes) per 256-thread block
    const int GB = (NN + 127) / 128;       // 391 gemm row-blocks

    // L1: buf = [x(0:128) | x1(128:256)]; gemm K=256 in-place -> cols 0:256
    spmm_kernel<2><<<SPMM_GRID, 256, 0, stream>>>(buf, 512, cnt, ell, dinv, buf + 128, 512);
    gemm_lds_kernel<8, 4, 256, 0, false><<<GB, 512, 0, stream>>>(
        buf, 512, WT1, bb1, nullptr, 0, buf, 512, NN, 1, 0, mode);
    // L2..L4: x1 into cols 256:512, gemm K=512 in-place -> cols 0:256
    spmm_kernel<4><<<SPMM_GRID, 256, 0, stream>>>(buf, 512, cnt, ell, dinv, buf + 256, 512);
    gemm_lds_kernel<16, 4, 512, 0, false><<<GB, 512, 0, stream>>>(
        buf, 512, WT2, bb2, nullptr, 0, buf, 512, NN, 1, 0, mode);
    spmm_kernel<4><<<SPMM_GRID, 256, 0, stream>>>(buf, 512, cnt, ell, dinv, buf + 256, 512);
    gemm_lds_kernel<16, 4, 512, 0, false><<<GB, 512, 0, stream>>>(
        buf, 512, WT2, bb2, nullptr, 0, buf, 512, NN, 1, 0, mode);
    spmm_kernel<4><<<SPMM_GRID, 256, 0, stream>>>(buf, 512, cnt, ell, dinv, buf + 256, 512);
    gemm_lds_kernel<16, 4, 512, 0, false><<<GB, 512, 0, stream>>>(
        buf, 512, WT2, bb2, nullptr, 0, buf, 512, NN, 1, 0, mode);
    // L5 swap: Â(h W3bot) = (Âh) W3bot — gather stream 512B -> 256B rows.
    //   z = h @ W3[256:512] -> buf cols 256:384 (bf16); reads cols 0:256 only
    //   x1z = Â z (FPL=2)   -> buf cols 384:512
    //   out = h @ W3[0:256] + x1z + b3 (f32 accum, single rounding) -> d_out
    gemm_lds_kernel<8, 2, 512, 256, false><<<GB, 256, 0, stream>>>(
        buf, 512, WT3, bbz, nullptr, 0, buf + 256, 512, NN, 0, 0, mode);
    spmm_kernel<2><<<SPMM_GRID, 256, 0, stream>>>(buf + 256, 512, cnt, ell, dinv,
                                                  buf + 384, 512);
    gemm_lds_kernel<8, 2, 512, 0, true><<<GB, 256, 0, stream>>>(
        buf, 512, WT3, bb3, buf + 384, 512, d_out, 128, NN, 0, 1, mode);
}